// Round 11
// baseline (229.505 us; speedup 1.0000x reference)
//
#include <hip/hip_runtime.h>
#include <hip/hip_bf16.h>
#include <cstdint>
#include <cstddef>

// Problem constants (fixed by reference)
#define BB 32
#define NN 8192
#define DIN 64
#define DOUT 128
#define NR 4
#define BN_EPS 1e-5f
#define CHUNKS 8  // NN / 1024 : one partial slot per (b, 1024-pt block)

typedef float nfloat4 __attribute__((ext_vector_type(4)));
typedef float floatx4 __attribute__((ext_vector_type(4)));
typedef short short8 __attribute__((ext_vector_type(8)));

// Workspace: float part[BB*CHUNKS][NR][DOUT] = 512 KB, fully overwritten.
//
// r11 theory (fits r0-r10): both kernels were DRAM-PAGE-limited, not
// latency/issue limited. k1 stage reads 64MB in 1KB strided granules
// (~1.1 TB/s); k2's first store pass writes 128MB in 4KB granules
// (~2 TB/s) -- r9's 6.4TB/s "g" was the L2-resident repeat passes, not
// first-touch. Fix: long sequential spans per block + XCD grouping.

__device__ inline void pack2(float a, float b, short8& dst, int idx) {
  __hip_bfloat162 h = __float22bfloat162_rn(make_float2(a, b));
  const unsigned int bits = *(unsigned int*)&h;
  dst[idx] = (short)(bits & 0xffffu);
  dst[idx + 1] = (short)(bits >> 16);
}

// LDS 16B-group swizzle (counter-verified conflict-free in r9)
__device__ inline int swz(int n) { return (n ^ (n >> 2) ^ (n >> 5)) & 7; }

// ---------------------------------------------------------------------------
// K1 (MFMA): r10 structure verbatim (best measured k1, ~67us) with ONE
// change: 1D grid + bijective XCD swizzle. HW round-robins blockIdx%8 over
// XCDs; we decode so XCD k owns batches 4k..4k+3 -> each XCD's 32 blocks
// collectively stream ONE contiguous 8MB x region (ordered page-friendly
// requests + L2 locality), instead of all 8 XCDs interleaving everywhere.
__global__ void __launch_bounds__(512) k_compute(
    const float* __restrict__ x, const float* __restrict__ W,
    const int* __restrict__ ring, float* __restrict__ part) {
  // bijective decode: 256 blocks = 8 xcd x 4 batches x 8 chunks
  const int g = (int)blockIdx.x;
  const int xcd = g & 7;
  const int idx = g >> 3;            // 0..31
  const int b = 4 * xcd + (idx >> 3);
  const int big = idx & 7;           // 1024-pt chunk index
  const int n0 = big * 1024;
  const int tid = (int)threadIdx.x;
  const int wave = tid >> 6;  // 0..7
  const int lane = tid & 63;
  const int quad = lane >> 4;
  const int l16 = lane & 15;
  const float* xb = x + (size_t)b * DIN * NN;
  const int* rgb = ring + (size_t)b * NN + n0;

  __shared__ short8 lx[2][256 * 8];  // 2 x 32 KB bf16 [n][dblk], swizzled

  // A fragments: afr[r][ks], A[m=l16 -> chan=w*16+l16][k=ks*32+quad*8+j]
  short8 afr[NR][2];
#pragma unroll
  for (int r = 0; r < NR; ++r) {
    const int chan = wave * 16 + l16;
    const float* wr = W + ((size_t)r * DOUT + chan) * DIN + quad * 8;
#pragma unroll
    for (int ks = 0; ks < 2; ++ks) {
      const float4 w0 = *(const float4*)&wr[ks * 32];
      const float4 w1 = *(const float4*)&wr[ks * 32 + 4];
      short8 a;
      pack2(w0.x, w0.y, a, 0);
      pack2(w0.z, w0.w, a, 2);
      pack2(w1.x, w1.y, a, 4);
      pack2(w1.z, w1.w, a, 6);
      afr[r][ks] = a;
    }
  }

  floatx4 rmax[NR];
#pragma unroll
  for (int r = 0; r < NR; ++r)
    rmax[r] = {-INFINITY, -INFINITY, -INFINITY, -INFINITY};

  auto LOADL = [&](nfloat4 (&L)[8], int c) {
    const float* base = xb + (size_t)(wave * 8) * NN + n0 + c * 256 + 4 * lane;
#pragma unroll
    for (int j = 0; j < 8; ++j)
      L[j] = *(const nfloat4*)&base[(size_t)j * NN];
  };
  auto PACKW = [&](int buf, const nfloat4 (&L)[8]) {
#pragma unroll
    for (int i = 0; i < 4; ++i) {
      short8 v;
      pack2(L[0][i], L[1][i], v, 0);
      pack2(L[2][i], L[3][i], v, 2);
      pack2(L[4][i], L[5][i], v, 4);
      pack2(L[6][i], L[7][i], v, 6);
      const int ni = 4 * lane + i;
      lx[buf][ni * 8 + (wave ^ swz(ni))] = v;
    }
  };
  auto TLOOP = [&](int buf, int c) {
#pragma unroll 4
    for (int T = 0; T < 16; ++T) {
      const int n = T * 16 + l16;
      const short8 b0 = lx[buf][n * 8 + (quad ^ swz(n))];
      const short8 b1 = lx[buf][n * 8 + ((4 + quad) ^ swz(n))];
      const int rr = rgb[c * 256 + n];
#pragma unroll
      for (int r = 0; r < NR; ++r) {
        floatx4 acc = {0.f, 0.f, 0.f, 0.f};
        acc = __builtin_amdgcn_mfma_f32_16x16x32_bf16(afr[r][0], b0, acc, 0, 0, 0);
        acc = __builtin_amdgcn_mfma_f32_16x16x32_bf16(afr[r][1], b1, acc, 0, 0, 0);
        if (rr == r) {
#pragma unroll
          for (int p = 0; p < 4; ++p) rmax[r][p] = fmaxf(rmax[r][p], acc[p]);
        }
      }
    }
  };

  // 4 sub-chunks, 2-deep pipeline, one barrier per iteration
  nfloat4 LA[8], LB[8];
  LOADL(LA, 0);
  PACKW(0, LA);
  LOADL(LB, 1);
  __syncthreads();
  TLOOP(0, 0);
  PACKW(1, LB);
  LOADL(LA, 2);
  __syncthreads();
  TLOOP(1, 1);
  PACKW(0, LA);
  LOADL(LB, 3);
  __syncthreads();
  TLOOP(0, 2);
  PACKW(1, LB);
  __syncthreads();
  TLOOP(1, 3);

  // epilogue: butterfly over 16 point-columns; l16==0 lanes store.
  // coverage: 8 waves x 4 quads x 4 p x 4 r = 512 = NR*DOUT.
  float* slot = part + (size_t)(b * CHUNKS + big) * NR * DOUT;
#pragma unroll
  for (int r = 0; r < NR; ++r) {
#pragma unroll
    for (int p = 0; p < 4; ++p) {
      float v = rmax[r][p];
      v = fmaxf(v, __shfl_xor(v, 1, 64));
      v = fmaxf(v, __shfl_xor(v, 2, 64));
      v = fmaxf(v, __shfl_xor(v, 4, 64));
      v = fmaxf(v, __shfl_xor(v, 8, 64));
      if (l16 == 0) {
        const int chan = wave * 16 + quad * 4 + p;
        slot[r * DOUT + chan] = v;
      }
    }
  }
}

// ---------------------------------------------------------------------------
// K2 (REWRITE for DRAM-page locality): block = (b, adjacent channel PAIR)
// -> writes two FULLY-SEQUENTIAL 32KB output rows in 8 tight iterations
// (old: 32 scattered 4KB segments at 32KB stride per block = page-miss
// per segment). All 8 ring int4 loads hoisted (independent, in flight
// together). XCD swizzle groups same-b blocks on one XCD: ring row is
// L2-cached once per XCD and each XCD streams a contiguous output region.
__global__ void __launch_bounds__(256) k_out(
    const float* __restrict__ bias, const float* __restrict__ gamma,
    const float* __restrict__ beta, const float* __restrict__ mean,
    const float* __restrict__ var, const int* __restrict__ ring,
    const float* __restrict__ part, float* __restrict__ out) {
  // bijective decode: 2048 blocks = 8 xcd x 4 batches x 64 chan-pairs
  const int g = (int)blockIdx.x;
  const int xcd = g & 7;
  const int idx = g >> 3;             // 0..255
  const int b = 4 * xcd + (idx >> 6);
  const int o0 = (idx & 63) * 2;      // channel pair o0, o0+1
  const int t = (int)threadIdx.x;

  // finalize the 8 (chan, ring) values; uniform addresses -> scalar loads
  float ya0, ya1, ya2, ya3, yb0, yb1, yb2, yb3;
  {
    float tmp[2][NR];
#pragma unroll
    for (int oo = 0; oo < 2; ++oo) {
#pragma unroll
      for (int r = 0; r < NR; ++r) {
        const int o = o0 + oo;
        const float* ps = part + (size_t)b * CHUNKS * NR * DOUT + r * DOUT + o;
        float raw = -INFINITY;
#pragma unroll
        for (int c = 0; c < CHUNKS; ++c)
          raw = fmaxf(raw, ps[(size_t)c * NR * DOUT]);
        const int tt = r * DOUT + o;
        const float sc = gamma[tt] * rsqrtf(var[tt] + BN_EPS);
        tmp[oo][r] = (raw + bias[tt] - mean[tt]) * sc + beta[tt];
      }
    }
    ya0 = tmp[0][0]; ya1 = tmp[0][1]; ya2 = tmp[0][2]; ya3 = tmp[0][3];
    yb0 = tmp[1][0]; yb1 = tmp[1][1]; yb2 = tmp[1][2]; yb3 = tmp[1][3];
  }

  const int* rgb = ring + (size_t)b * NN;
  float* r0 = out + ((size_t)b * DOUT + o0) * NN;
  float* r1 = r0 + NN;

  // hoist all 8 independent ring int4 loads (static indices only)
  int4 rg[8];
#pragma unroll
  for (int it = 0; it < 8; ++it)
    rg[it] = *(const int4*)&rgb[it * 1024 + t * 4];

  // 8 tight iterations: each writes 4KB (block-wide) at ascending n for
  // BOTH rows -> 2 long sequential streams, pages stay open.
#pragma unroll
  for (int it = 0; it < 8; ++it) {
    const int n = it * 1024 + t * 4;
    nfloat4 va, vb;
    { const int r = rg[it].x;
      const float la = (r & 1) ? ya1 : ya0, ha = (r & 1) ? ya3 : ya2;
      const float lb = (r & 1) ? yb1 : yb0, hb = (r & 1) ? yb3 : yb2;
      va.x = (r & 2) ? ha : la; vb.x = (r & 2) ? hb : lb; }
    { const int r = rg[it].y;
      const float la = (r & 1) ? ya1 : ya0, ha = (r & 1) ? ya3 : ya2;
      const float lb = (r & 1) ? yb1 : yb0, hb = (r & 1) ? yb3 : yb2;
      va.y = (r & 2) ? ha : la; vb.y = (r & 2) ? hb : lb; }
    { const int r = rg[it].z;
      const float la = (r & 1) ? ya1 : ya0, ha = (r & 1) ? ya3 : ya2;
      const float lb = (r & 1) ? yb1 : yb0, hb = (r & 1) ? yb3 : yb2;
      va.z = (r & 2) ? ha : la; vb.z = (r & 2) ? hb : lb; }
    { const int r = rg[it].w;
      const float la = (r & 1) ? ya1 : ya0, ha = (r & 1) ? ya3 : ya2;
      const float lb = (r & 1) ? yb1 : yb0, hb = (r & 1) ? yb3 : yb2;
      va.w = (r & 2) ? ha : la; vb.w = (r & 2) ? hb : lb; }
    *(nfloat4*)&r0[n] = va;
    *(nfloat4*)&r1[n] = vb;
  }
}

// ---------------------------------------------------------------------------
extern "C" void kernel_launch(void* const* d_in, const int* in_sizes, int n_in,
                              void* d_out, int out_size, void* d_ws, size_t ws_size,
                              hipStream_t stream) {
  const float* x = (const float*)d_in[0];
  const int* ring = (const int*)d_in[1];
  const float* W = (const float*)d_in[2];
  const float* bias = (const float*)d_in[3];
  const float* gamma = (const float*)d_in[4];
  const float* beta = (const float*)d_in[5];
  const float* mean = (const float*)d_in[6];
  const float* var = (const float*)d_in[7];
  float* out = (float*)d_out;

  float* part = (float*)d_ws;  // 512 KB, fully overwritten -> no memset

  k_compute<<<dim3(256), 512, 0, stream>>>(x, W, ring, part);
  k_out<<<dim3(2048), 256, 0, stream>>>(bias, gamma, beta, mean,
                                        var, ring, part, out);
}

// Round 12
// 220.058 us; speedup vs baseline: 1.0429x; 1.0429x over previous
//
#include <hip/hip_runtime.h>
#include <hip/hip_bf16.h>
#include <cstdint>
#include <cstddef>

// Problem constants (fixed by reference)
#define BB 32
#define NN 8192
#define DIN 64
#define DOUT 128
#define NR 4
#define BN_EPS 1e-5f
#define CHUNKS 16  // NN / 512 : one partial slot per (b, 512-pt block)

typedef float nfloat4 __attribute__((ext_vector_type(4)));
typedef float floatx4 __attribute__((ext_vector_type(4)));
typedef short short8 __attribute__((ext_vector_type(8)));

// Workspace: float part[BB*CHUNKS][NR][DOUT] = 1 MB, fully overwritten.
//
// r12 ledger (from r9 instrumentation + r0-r11 invariants):
//   k1 T-loop ~14us/pass, k2 store pass ~22us  -> near floors
//   k1 "fixed" ~65us: the ONE untouched-from-r0 component is the butterfly
//   epilogue: 128 serially-dependent ds_bpermute round-trips per wave
//   (~120cy each). r10 halved the count and k1 dropped 79->67 -- matching
//   the epilogue, not the stage. This round replaces it with a cooperative
//   LDS transpose-reduce (~1-2us) and runs 2 independent blocks/CU so
//   barriers of one block hide under the other's stage.

__device__ inline void pack2(float a, float b, short8& dst, int idx) {
  __hip_bfloat162 h = __float22bfloat162_rn(make_float2(a, b));
  const unsigned int bits = *(unsigned int*)&h;
  dst[idx] = (short)(bits & 0xffffu);
  dst[idx + 1] = (short)(bits >> 16);
}

// LDS 16B-group swizzle (counter-verified conflict-free in r9)
__device__ inline int swz(int n) { return (n ^ (n >> 2) ^ (n >> 5)) & 7; }

// ---------------------------------------------------------------------------
// K1 (MFMA): block = (b, 512-pt chunk), 8 waves, grid 16x32 = 512 blocks
// = 2 blocks/CU (LDS 64KB/block). Wave w owns chan-tile w (chan=w*16+l16)
// and stages d-rows w*8..w*8+7. 2 sub-chunks of 256 pts, double-buffered:
// loads for sub-chunk 1 fly under tloop(0). Epilogue: LDS transpose-reduce
// (aliases the staging buffer) -- no shfl butterflies.
__global__ void __launch_bounds__(512, 4) k_compute(
    const float* __restrict__ x, const float* __restrict__ W,
    const int* __restrict__ ring, float* __restrict__ part) {
  const int b = blockIdx.y;
  const int chunk = blockIdx.x;  // 512-pt chunk index
  const int n0 = chunk * 512;
  const int tid = (int)threadIdx.x;
  const int wave = tid >> 6;  // 0..7
  const int lane = tid & 63;
  const int quad = lane >> 4;
  const int l16 = lane & 15;
  const float* xb = x + (size_t)b * DIN * NN;
  const int* rgb = ring + (size_t)b * NN + n0;

  __shared__ short8 lx[2][256 * 8];  // 2 x 32 KB bf16 [n][dblk], swizzled

  // A fragments: afr[r][ks], A[m=l16 -> chan=w*16+l16][k=ks*32+quad*8+j]
  short8 afr[NR][2];
#pragma unroll
  for (int r = 0; r < NR; ++r) {
    const int chan = wave * 16 + l16;
    const float* wr = W + ((size_t)r * DOUT + chan) * DIN + quad * 8;
#pragma unroll
    for (int ks = 0; ks < 2; ++ks) {
      const float4 w0 = *(const float4*)&wr[ks * 32];
      const float4 w1 = *(const float4*)&wr[ks * 32 + 4];
      short8 a;
      pack2(w0.x, w0.y, a, 0);
      pack2(w0.z, w0.w, a, 2);
      pack2(w1.x, w1.y, a, 4);
      pack2(w1.z, w1.w, a, 6);
      afr[r][ks] = a;
    }
  }

  floatx4 rmax[NR];
#pragma unroll
  for (int r = 0; r < NR; ++r)
    rmax[r] = {-INFINITY, -INFINITY, -INFINITY, -INFINITY};

  auto LOADL = [&](nfloat4 (&L)[8], int c) {
    const float* base = xb + (size_t)(wave * 8) * NN + n0 + c * 256 + 4 * lane;
#pragma unroll
    for (int j = 0; j < 8; ++j)
      L[j] = *(const nfloat4*)&base[(size_t)j * NN];
  };
  auto PACKW = [&](int buf, const nfloat4 (&L)[8]) {
#pragma unroll
    for (int i = 0; i < 4; ++i) {
      short8 v;
      pack2(L[0][i], L[1][i], v, 0);
      pack2(L[2][i], L[3][i], v, 2);
      pack2(L[4][i], L[5][i], v, 4);
      pack2(L[6][i], L[7][i], v, 6);
      const int ni = 4 * lane + i;
      lx[buf][ni * 8 + (wave ^ swz(ni))] = v;
    }
  };
  auto TLOOP = [&](int buf, int c) {
#pragma unroll 4
    for (int T = 0; T < 16; ++T) {
      const int n = T * 16 + l16;
      const short8 b0 = lx[buf][n * 8 + (quad ^ swz(n))];        // d=quad*8+j
      const short8 b1 = lx[buf][n * 8 + ((4 + quad) ^ swz(n))];  // d=32+...
      const int rr = rgb[c * 256 + n];
#pragma unroll
      for (int r = 0; r < NR; ++r) {
        floatx4 acc = {0.f, 0.f, 0.f, 0.f};
        acc = __builtin_amdgcn_mfma_f32_16x16x32_bf16(afr[r][0], b0, acc, 0, 0, 0);
        acc = __builtin_amdgcn_mfma_f32_16x16x32_bf16(afr[r][1], b1, acc, 0, 0, 0);
        if (rr == r) {  // exec-masked fold; MFMAs stay convergent
#pragma unroll
          for (int p = 0; p < 4; ++p) rmax[r][p] = fmaxf(rmax[r][p], acc[p]);
        }
      }
    }
  };

  // 2 sub-chunks, 2-deep pipeline
  nfloat4 LA[8], LB[8];
  LOADL(LA, 0);
  PACKW(0, LA);
  LOADL(LB, 1);  // flies under tloop(0)
  __syncthreads();
  TLOOP(0, 0);
  PACKW(1, LB);
  __syncthreads();
  TLOOP(1, 1);

  // ---- epilogue: cooperative LDS transpose-reduce (no shfl chains).
  // Thread (w,q,l16) holds rmax[r][p] = partial max for chan w*16+q*4+p
  // over its 16-pt column l16. Write red[v=4r+p][tid] (conflict-free:
  // consecutive tids), barrier, then thread t=(w, l) with r=l>>4,
  // p=(l>>2)&3, q=l&3 reads the 16 l16-values as 4x ds_read_b128 and
  // folds 15 v_max -> one plain store to the block's private slot.
  __syncthreads();  // all TLOOP(1) lx reads done; safe to alias lx as red
  float* red = (float*)&lx[0][0];  // 16 x 520 floats = 33 KB <= 64 KB
#pragma unroll
  for (int r = 0; r < NR; ++r)
#pragma unroll
    for (int p = 0; p < 4; ++p)
      red[(r * 4 + p) * 520 + tid] = rmax[r][p];
  __syncthreads();

  {
    const int l = tid & 63;
    const int w = tid >> 6;
    const int r = l >> 4;
    const int p = (l >> 2) & 3;
    const int q = l & 3;
    const float* src = &red[(r * 4 + p) * 520 + w * 64 + q * 16];
    nfloat4 a = *(const nfloat4*)&src[0];
    nfloat4 c = *(const nfloat4*)&src[4];
    nfloat4 d = *(const nfloat4*)&src[8];
    nfloat4 e = *(const nfloat4*)&src[12];
    float v = fmaxf(fmaxf(fmaxf(a.x, a.y), fmaxf(a.z, a.w)),
                    fmaxf(fmaxf(c.x, c.y), fmaxf(c.z, c.w)));
    v = fmaxf(v, fmaxf(fmaxf(d.x, d.y), fmaxf(d.z, d.w)));
    v = fmaxf(v, fmaxf(fmaxf(e.x, e.y), fmaxf(e.z, e.w)));
    float* slot = part + (size_t)(b * CHUNKS + chunk) * NR * DOUT;
    slot[r * DOUT + w * 16 + q * 4 + p] = v;
  }
}

// ---------------------------------------------------------------------------
// K2: r8 verbatim (best measured k2), CHUNKS=16.
__global__ void __launch_bounds__(256) k_out(
    const float* __restrict__ bias, const float* __restrict__ gamma,
    const float* __restrict__ beta, const float* __restrict__ mean,
    const float* __restrict__ var, const int* __restrict__ ring,
    const float* __restrict__ part, float* __restrict__ out) {
  const int b = blockIdx.z;
  const int og = blockIdx.y;  // 32-channel group
  const int n0 = blockIdx.x * 1024;
  const int t = (int)threadIdx.x;

  __shared__ float lut[32 * NR * 32];  // [oo][r][c32], 16 KB
  {
    const int oo = t >> 3;
    const int r = (t >> 1) & 3;
    const int c0 = (t & 1) * 16;
    const int o = og * 32 + oo;
    const float* ps = part + (size_t)b * CHUNKS * NR * DOUT + r * DOUT + o;
    float raw = -INFINITY;
#pragma unroll
    for (int c = 0; c < CHUNKS; ++c)
      raw = fmaxf(raw, ps[(size_t)c * NR * DOUT]);
    const int tt = r * DOUT + o;
    const float sc = gamma[tt] * rsqrtf(var[tt] + BN_EPS);
    const float val = (raw + bias[tt] - mean[tt]) * sc + beta[tt];
    nfloat4 v4 = {val, val, val, val};
    float* dst = &lut[(oo * NR + r) * 32 + c0];
#pragma unroll
    for (int k = 0; k < 4; ++k) *(nfloat4*)&dst[k * 4] = v4;
  }
  __syncthreads();

  const int n = n0 + t * 4;
  const int4 rg = *(const int4*)&ring[(size_t)b * NN + n];
  const int l31 = t & 31;
  const float* p0 = &lut[rg.x * 32 + l31];
  const float* p1 = &lut[rg.y * 32 + l31];
  const float* p2 = &lut[rg.z * 32 + l31];
  const float* p3 = &lut[rg.w * 32 + l31];
  float* orow = out + ((size_t)b * DOUT + og * 32) * NN + n;

#pragma unroll 8
  for (int oo = 0; oo < 32; ++oo) {
    nfloat4 v;
    v.x = p0[oo * 128];  // conflict-free replicated-LUT gather
    v.y = p1[oo * 128];
    v.z = p2[oo * 128];
    v.w = p3[oo * 128];
    *(nfloat4*)(orow + (size_t)oo * NN) = v;
  }
}

// ---------------------------------------------------------------------------
extern "C" void kernel_launch(void* const* d_in, const int* in_sizes, int n_in,
                              void* d_out, int out_size, void* d_ws, size_t ws_size,
                              hipStream_t stream) {
  const float* x = (const float*)d_in[0];
  const int* ring = (const int*)d_in[1];
  const float* W = (const float*)d_in[2];
  const float* bias = (const float*)d_in[3];
  const float* gamma = (const float*)d_in[4];
  const float* beta = (const float*)d_in[5];
  const float* mean = (const float*)d_in[6];
  const float* var = (const float*)d_in[7];
  float* out = (float*)d_out;

  float* part = (float*)d_ws;  // 1 MB, fully overwritten -> no memset

  k_compute<<<dim3(CHUNKS, BB), 512, 0, stream>>>(x, W, ring, part);
  k_out<<<dim3(NN / 1024, DOUT / 32, BB), 256, 0, stream>>>(bias, gamma, beta, mean,
                                                            var, ring, part, out);
}